// Round 7
// baseline (369.568 us; speedup 1.0000x reference)
//
#include <hip/hip_runtime.h>
#include <math.h>

// ---------------------------------------------------------------------------
// RecursiveEncoder forward, fp16 MFMA pipeline. Round 7 (= R6 + slot-rotation
// fix in k2's cross-stage weight prefetch: loadA(nxt, s, s), chunk==slot).
//  - transposed GEMMs (A=weights, B=activations) with packed f16x4 epilogues
//  - padded-row layouts everywhere (no XOR swizzle, contiguous global stores)
//  - k1: 4-deep weight reg-pipeline issued at kernel top; unrolled masked
//    maxpool (10 independent b128 LDS reads, cndmask)
//  - k2: continuous weight pipeline across the 4 GEMM stages
// ---------------------------------------------------------------------------

#define NPAR  32768
#define LDA1  328                         // k1 LDS activation row (halfs)
#define LDX   264                         // xbuf row / k2 LDS row (halfs)
// ws layout (halfs):
#define W1T_OFF   0                       // [256 feat][320 k]
#define W2T_OFF   81920                   // 4 x [256 feat][256 k]
#define WBX_OFF   (81920 + 4*65536)       // [256 feat][32 k]   = 344064
#define XBUF_OFF  (WBX_OFF + 8192)        // [NPAR][264] = 352256

typedef _Float16 f16;
typedef _Float16 f16x4 __attribute__((ext_vector_type(4)));
typedef _Float16 f16x8 __attribute__((ext_vector_type(8)));
typedef unsigned short u16x8 __attribute__((ext_vector_type(8)));
typedef float    f32x4 __attribute__((ext_vector_type(4)));

__device__ __forceinline__ void async16(const void* g, void* l) {
    __builtin_amdgcn_global_load_lds((const __attribute__((address_space(1))) void*)g,
                                     (__attribute__((address_space(3))) void*)l, 16, 0, 0);
}
__device__ __forceinline__ f32x4 mfma16(f16x8 a, f16x8 b, f32x4 c) {
    return __builtin_amdgcn_mfma_f32_16x16x32_f16(a, b, c, 0, 0, 0);
}
__device__ __forceinline__ f16x4 pack4(float a, float b, float c, float d) {
    f16x4 r; r[0] = (f16)a; r[1] = (f16)b; r[2] = (f16)c; r[3] = (f16)d;
    return r;
}

// ---------------- kconv: coalesced writes, scattered (L2-hot) reads ----------
__global__ void kconv(const float* __restrict__ W1, const float* __restrict__ W2,
                      const float* __restrict__ Ws1, const float* __restrict__ Wmu,
                      const float* __restrict__ Wvar, const float* __restrict__ Wbox,
                      f16* __restrict__ ws) {
    int idx = blockIdx.x * 256 + threadIdx.x;
    if (idx < 81920) {                       // w1t[n][k] = W1[k][n], k<320
        int n = idx / 320, k = idx % 320;
        ws[idx] = (f16)W1[k * 256 + n];
    } else if (idx < WBX_OFF) {              // 4 x [n][k] = W[k][n]
        int r = idx - 81920;
        int wsel = r >> 16, r2 = r & 65535;
        int n = r2 >> 8, k = r2 & 255;
        const float* s = (wsel == 0) ? W2 : (wsel == 1) ? Ws1 : (wsel == 2) ? Wmu : Wvar;
        ws[idx] = (f16)s[k * 256 + n];
    } else if (idx < XBUF_OFF) {             // wbx[n][32], zero pad k>=10
        int r = idx - WBX_OFF;
        int n = r >> 5, k = r & 31;
        ws[idx] = (k < 10) ? (f16)Wbox[k * 256 + n] : (f16)0.f;
    }
}

// ---------------- k1: leaf + K=320 GEMM (one-hot fused) + max-pool -----------
// block = 8 parents = 80 child rows; grid 4096; 256 thr (4 waves x 64 feats)
__global__ __launch_bounds__(256, 3)
void k1(const float* __restrict__ box, const float* __restrict__ bbox,
        const float* __restrict__ b1, const int* __restrict__ sem,
        const int* __restrict__ nch, const f16* __restrict__ wsh,
        f16* __restrict__ xbuf) {
    __shared__ __align__(16) f16 lA[80 * LDA1];   // 52480 B

    int tid = threadIdx.x, blk = blockIdx.x;
    int w = tid >> 6, lane = tid & 63, q = lane >> 4, r16 = lane & 15;
    const f16* w1t = wsh + W1T_OFF;
    const f16* wbx = wsh + WBX_OFF;

    // ---- issue ALL long-latency loads first -------------------------------
    f16x8 aw[4][4];                              // 4-deep weight pipeline
    auto loadA = [&](int c, int s) {
        #pragma unroll
        for (int mt = 0; mt < 4; mt++)
            aw[s][mt] = *(const f16x8*)&w1t[(w * 64 + mt * 16 + r16) * 320 + c * 32 + q * 8];
    };
    loadA(0, 0); loadA(1, 1); loadA(2, 2); loadA(3, 3);

    int nc  = nch[blk * 8 + (tid >> 5)];         // for maxpool (early)
    int sid = (tid < 80) ? sem[blk * 80 + tid] : 0;

    f32x4 acc[4][5];                             // [mt(feat)][nt(child)]

    // ---- leaf: D[feat][child] = Wbox^T(A) x box^T(B), K=32 zero-padded
    {
        f16x8 ab[4], bb[5];
        #pragma unroll
        for (int mt = 0; mt < 4; mt++)
            ab[mt] = *(const f16x8*)&wbx[(w * 64 + mt * 16 + r16) * 32 + q * 8];
        #pragma unroll
        for (int nt = 0; nt < 5; nt++) {
            const float* bp = box + (size_t)blk * 800 + (nt * 16 + r16) * 10;
            float v[8] = {0.f, 0.f, 0.f, 0.f, 0.f, 0.f, 0.f, 0.f};
            if (q == 0) {
                float2 t0 = *(const float2*)(bp + 0), t1 = *(const float2*)(bp + 2);
                float2 t2 = *(const float2*)(bp + 4), t3 = *(const float2*)(bp + 6);
                v[0] = t0.x; v[1] = t0.y; v[2] = t1.x; v[3] = t1.y;
                v[4] = t2.x; v[5] = t2.y; v[6] = t3.x; v[7] = t3.y;
            } else if (q == 1) {
                float2 t = *(const float2*)(bp + 8);
                v[0] = t.x; v[1] = t.y;
            }
            f16x8 t;
            #pragma unroll
            for (int j = 0; j < 8; j++) t[j] = (f16)v[j];
            bb[nt] = t;
        }
        #pragma unroll
        for (int mt = 0; mt < 4; mt++)
            #pragma unroll
            for (int nt = 0; nt < 5; nt++)
                acc[mt][nt] = mfma16(ab[mt], bb[nt], (f32x4){0.f, 0.f, 0.f, 0.f});
    }
    // leaf epilogue: relu(+bbox), packed b64 -> lA[child][feat]
    #pragma unroll
    for (int mt = 0; mt < 4; mt++) {
        int fb = w * 64 + mt * 16 + q * 4;
        float4 b4 = *(const float4*)&bbox[fb];
        #pragma unroll
        for (int nt = 0; nt < 5; nt++) {
            int child = nt * 16 + r16;
            f16x4 p = pack4(fmaxf(acc[mt][nt][0] + b4.x, 0.f),
                            fmaxf(acc[mt][nt][1] + b4.y, 0.f),
                            fmaxf(acc[mt][nt][2] + b4.z, 0.f),
                            fmaxf(acc[mt][nt][3] + b4.w, 0.f));
            *(f16x4*)&lA[child * LDA1 + fb] = p;
        }
    }
    // one-hot region k=256..319 (each row owned by one thread)
    if (tid < 80) {
        f16x8 z = {(f16)0.f, (f16)0.f, (f16)0.f, (f16)0.f, (f16)0.f, (f16)0.f, (f16)0.f, (f16)0.f};
        #pragma unroll
        for (int j = 0; j < 8; j++) *(f16x8*)&lA[tid * LDA1 + 256 + j * 8] = z;
        lA[tid * LDA1 + 256 + sid] = (f16)1.f;
    }

    // ---- main GEMM: D[feat][child], K=320, weights streamed 4-deep ----------
    #pragma unroll
    for (int mt = 0; mt < 4; mt++)
        #pragma unroll
        for (int nt = 0; nt < 5; nt++) acc[mt][nt] = (f32x4){0.f, 0.f, 0.f, 0.f};

    __syncthreads();                             // lA complete
    #pragma unroll
    for (int c = 0; c < 10; c++) {
        f16x8 bl[5];
        int kk = c * 32 + q * 8;
        #pragma unroll
        for (int nt = 0; nt < 5; nt++)
            bl[nt] = *(const f16x8*)&lA[(nt * 16 + r16) * LDA1 + kk];
        int s = c & 3;
        #pragma unroll
        for (int mt = 0; mt < 4; mt++)
            #pragma unroll
            for (int nt = 0; nt < 5; nt++) acc[mt][nt] = mfma16(aw[s][mt], bl[nt], acc[mt][nt]);
        if (c + 4 < 10) loadA(c + 4, s);
    }
    __syncthreads();                             // all lA reads done

    // epilogue: relu(+b1), packed b64 -> lA[child][feat] (cols 0..255)
    #pragma unroll
    for (int mt = 0; mt < 4; mt++) {
        int fb = w * 64 + mt * 16 + q * 4;
        float4 b4 = *(const float4*)&b1[fb];
        #pragma unroll
        for (int nt = 0; nt < 5; nt++) {
            int child = nt * 16 + r16;
            f16x4 p = pack4(fmaxf(acc[mt][nt][0] + b4.x, 0.f),
                            fmaxf(acc[mt][nt][1] + b4.y, 0.f),
                            fmaxf(acc[mt][nt][2] + b4.z, 0.f),
                            fmaxf(acc[mt][nt][3] + b4.w, 0.f));
            *(f16x4*)&lA[child * LDA1 + fb] = p;
        }
    }
    __syncthreads();

    // masked max over children: 10 independent b128 reads + cndmask -> xbuf
    {
        int p = tid >> 5, g = tid & 31;
        u16x8 m = {0, 0, 0, 0, 0, 0, 0, 0};
        #pragma unroll
        for (int j = 0; j < 10; j++) {
            u16x8 v = *(const u16x8*)&lA[(p * 10 + j) * LDA1 + g * 8];
            u16x8 zz = {0, 0, 0, 0, 0, 0, 0, 0};
            v = (j < nc) ? v : zz;               // relu => nonneg => u16 max ok
            m = __builtin_elementwise_max(m, v);
        }
        int gp = blk * 8 + p;
        *(u16x8*)&xbuf[(size_t)gp * LDX + g * 8] = m;   // contiguous 16B/lane
    }
}

// ---------------- k2: sampler chain, continuous weight pipeline --------------
// block = 32 parents; grid 1024; 256 thr (4 waves x 64 feats)
__global__ __launch_bounds__(256, 3)
void k2(const f16* __restrict__ xbuf, const f16* __restrict__ wsh,
        const float* __restrict__ b2, const float* __restrict__ bs1,
        const float* __restrict__ bmu, const float* __restrict__ bvar,
        const float* __restrict__ eps, float* __restrict__ out) {
    __shared__ __align__(16) f16 actA[32 * LDX];   // 16896 B
    __shared__ __align__(16) f16 actB[32 * LDX];

    int tid = threadIdx.x, blk = blockIdx.x;
    int w = tid >> 6, lane = tid & 63, q = lane >> 4, r16 = lane & 15;
    const f16* w2t   = wsh + W2T_OFF;
    const f16* ws1t  = w2t + 65536;
    const f16* wmut  = w2t + 2 * 65536;
    const f16* wvart = w2t + 3 * 65536;

    {   // stage x tile (16896 B flat, padded rows included)
        const char* src = (const char*)(xbuf + (size_t)blk * 32 * LDX);
        #pragma unroll
        for (int j = 0; j < 5; j++) {
            int idx = tid + j * 256;
            if (idx < 1056) async16(src + idx * 16, (char*)actA + idx * 16);
        }
    }

    f32x4 acc[4][2];
    f16x8 aw[3][4];
    auto loadA = [&](const f16* wt, int c, int s) {
        #pragma unroll
        for (int mt = 0; mt < 4; mt++)
            aw[s][mt] = *(const f16x8*)&wt[(w * 64 + mt * 16 + r16) * 256 + c * 32 + q * 8];
    };
    // gemm: consumes cur (chunks 0..2 preloaded, chunk c in slot c%3); tail
    // iters (c=5,6,7 -> s=2,0,1) prefetch nxt's chunk s into slot s, so the
    // next gemm again finds chunk c in slot c%3.
    auto gemm = [&](const f16* A, const f16* cur, const f16* nxt) {
        #pragma unroll
        for (int mt = 0; mt < 4; mt++)
            #pragma unroll
            for (int nt = 0; nt < 2; nt++) acc[mt][nt] = (f32x4){0.f, 0.f, 0.f, 0.f};
        #pragma unroll
        for (int c = 0; c < 8; c++) {
            f16x8 bl[2];
            int kk = c * 32 + q * 8;
            #pragma unroll
            for (int nt = 0; nt < 2; nt++)
                bl[nt] = *(const f16x8*)&A[(nt * 16 + r16) * LDX + kk];
            int s = c % 3;
            #pragma unroll
            for (int mt = 0; mt < 4; mt++)
                #pragma unroll
                for (int nt = 0; nt < 2; nt++) acc[mt][nt] = mfma16(aw[s][mt], bl[nt], acc[mt][nt]);
            if (c + 3 < 8) loadA(cur, c + 3, s);
            else if (nxt)  loadA(nxt, s, s);     // chunk == slot (FIX)
        }
    };
    auto store_act = [&](f16* dst, const float* bias) {
        #pragma unroll
        for (int mt = 0; mt < 4; mt++) {
            int fb = w * 64 + mt * 16 + q * 4;
            float4 b4 = *(const float4*)&bias[fb];
            #pragma unroll
            for (int nt = 0; nt < 2; nt++) {
                int par = nt * 16 + r16;
                f16x4 p = pack4(fmaxf(acc[mt][nt][0] + b4.x, 0.f),
                                fmaxf(acc[mt][nt][1] + b4.y, 0.f),
                                fmaxf(acc[mt][nt][2] + b4.z, 0.f),
                                fmaxf(acc[mt][nt][3] + b4.w, 0.f));
                *(f16x4*)&dst[par * LDX + fb] = p;
            }
        }
    };

    // stage1: parent_feat = relu(x @ W2 + b2) -> actB
    loadA(w2t, 0, 0); loadA(w2t, 1, 1); loadA(w2t, 2, 2);
    __syncthreads();                             // drains actA staging
    gemm(actA, w2t, ws1t);
    store_act(actB, b2);
    __syncthreads();

    // stage2: enc = relu(parent @ Ws1 + bs1) -> actA
    gemm(actB, ws1t, wmut);
    store_act(actA, bs1);
    __syncthreads();

    // stage3: mu -> regs (prefetches wvart in tail)
    gemm(actA, wmut, wvart);
    f32x4 mu[4][2];
    #pragma unroll
    for (int mt = 0; mt < 4; mt++)
        #pragma unroll
        for (int nt = 0; nt < 2; nt++) mu[mt][nt] = acc[mt][nt];

    // stage4: logvar (actA unchanged: no barrier, pipeline stays hot)
    gemm(actA, wvart, nullptr);

    // fused sampler epilogue, float4 io
    #pragma unroll
    for (int mt = 0; mt < 4; mt++) {
        int fb = w * 64 + mt * 16 + q * 4;
        float4 bm4 = *(const float4*)&bmu[fb];
        float4 bv4 = *(const float4*)&bvar[fb];
        #pragma unroll
        for (int nt = 0; nt < 2; nt++) {
            size_t gp = (size_t)blk * 32 + nt * 16 + r16;
            float4 ev = *(const float4*)&eps[gp * 256 + fb];
            float m0 = mu[mt][nt][0] + bm4.x, l0 = acc[mt][nt][0] + bv4.x;
            float m1 = mu[mt][nt][1] + bm4.y, l1 = acc[mt][nt][1] + bv4.y;
            float m2 = mu[mt][nt][2] + bm4.z, l2 = acc[mt][nt][2] + bv4.z;
            float m3 = mu[mt][nt][3] + bm4.w, l3 = acc[mt][nt][3] + bv4.w;
            float e0 = expf(l0), e1 = expf(l1), e2 = expf(l2), e3 = expf(l3);
            float4 s4 = {ev.x * sqrtf(e0) + m0, ev.y * sqrtf(e1) + m1,
                         ev.z * sqrtf(e2) + m2, ev.w * sqrtf(e3) + m3};
            float4 k4 = {1.f + l0 - m0 * m0 - e0, 1.f + l1 - m1 * m1 - e1,
                         1.f + l2 - m2 * m2 - e2, 1.f + l3 - m3 * m3 - e3};
            *(float4*)&out[gp * 512 + fb]       = s4;
            *(float4*)&out[gp * 512 + 256 + fb] = k4;
        }
    }
}

// ---------------------------------------------------------------------------
extern "C" void kernel_launch(void* const* d_in, const int* in_sizes, int n_in,
                              void* d_out, int out_size, void* d_ws, size_t ws_size,
                              hipStream_t stream) {
    const float* box  = (const float*)d_in[0];
    const float* eps  = (const float*)d_in[1];
    const float* Wbox = (const float*)d_in[2];
    const float* bbox = (const float*)d_in[3];
    const float* W1   = (const float*)d_in[4];
    const float* b1   = (const float*)d_in[5];
    const float* W2   = (const float*)d_in[6];
    const float* b2   = (const float*)d_in[7];
    const float* Ws1  = (const float*)d_in[8];
    const float* bs1  = (const float*)d_in[9];
    const float* Wmu  = (const float*)d_in[10];
    const float* bmu  = (const float*)d_in[11];
    const float* Wvar = (const float*)d_in[12];
    const float* bvar = (const float*)d_in[13];
    const int*   sem  = (const int*)d_in[14];
    const int*   nch  = (const int*)d_in[15];

    f16* wsh  = (f16*)d_ws;
    f16* xbuf = wsh + XBUF_OFF;

    kconv<<<XBUF_OFF / 256, 256, 0, stream>>>(W1, W2, Ws1, Wmu, Wvar, Wbox, wsh);
    k1<<<NPAR / 8, 256, 0, stream>>>(box, bbox, b1, sem, nch, wsh, xbuf);
    k2<<<NPAR / 32, 256, 0, stream>>>(xbuf, wsh, b2, bs1, bmu, bvar, eps, (float*)d_out);
}

// Round 8
// 319.809 us; speedup vs baseline: 1.1556x; 1.1556x over previous
//
#include <hip/hip_runtime.h>
#include <math.h>

// ---------------------------------------------------------------------------
// RecursiveEncoder forward, fp16 MFMA pipeline. Round 8: verified-best hybrid.
//  - k1: padded LDS rows (R3-clean traffic) + transposed GEMM + packed b64
//    epilogues (R5 VALU win) + 3-deep POST-LEAF weight preload (R5: stays in
//    registers; R7's 4-deep top-hoisted version spilled to scratch -> 268 MB
//    of parasitic traffic) + dense 512-B-aligned xbuf rows (full-line stores).
//  - k2: R7-verified ping-pong + continuous weight pipeline; x-tile staged
//    via REGISTERS into padded LDS rows (global stays dense/coalesced).
// ---------------------------------------------------------------------------

#define NPAR  32768
#define LDA1  328                         // k1 LDS activation row (halfs)
#define LDX   264                         // k2 LDS act row (halfs)
// ws layout (halfs):
#define W1T_OFF   0                       // [256 feat][320 k]
#define W2T_OFF   81920                   // 4 x [256 feat][256 k]
#define WBX_OFF   (81920 + 4*65536)       // [256 feat][32 k]   = 344064
#define XBUF_OFF  (WBX_OFF + 8192)        // [NPAR][256] dense  = 352256

typedef _Float16 f16;
typedef _Float16 f16x4 __attribute__((ext_vector_type(4)));
typedef _Float16 f16x8 __attribute__((ext_vector_type(8)));
typedef unsigned short u16x8 __attribute__((ext_vector_type(8)));
typedef float    f32x4 __attribute__((ext_vector_type(4)));

__device__ __forceinline__ f32x4 mfma16(f16x8 a, f16x8 b, f32x4 c) {
    return __builtin_amdgcn_mfma_f32_16x16x32_f16(a, b, c, 0, 0, 0);
}
__device__ __forceinline__ f16x4 pack4(float a, float b, float c, float d) {
    f16x4 r; r[0] = (f16)a; r[1] = (f16)b; r[2] = (f16)c; r[3] = (f16)d;
    return r;
}

// ---------------- kconv: coalesced writes, scattered (L2-hot) reads ----------
__global__ void kconv(const float* __restrict__ W1, const float* __restrict__ W2,
                      const float* __restrict__ Ws1, const float* __restrict__ Wmu,
                      const float* __restrict__ Wvar, const float* __restrict__ Wbox,
                      f16* __restrict__ ws) {
    int idx = blockIdx.x * 256 + threadIdx.x;
    if (idx < 81920) {                       // w1t[n][k] = W1[k][n], k<320
        int n = idx / 320, k = idx % 320;
        ws[idx] = (f16)W1[k * 256 + n];
    } else if (idx < WBX_OFF) {              // 4 x [n][k] = W[k][n]
        int r = idx - 81920;
        int wsel = r >> 16, r2 = r & 65535;
        int n = r2 >> 8, k = r2 & 255;
        const float* s = (wsel == 0) ? W2 : (wsel == 1) ? Ws1 : (wsel == 2) ? Wmu : Wvar;
        ws[idx] = (f16)s[k * 256 + n];
    } else if (idx < XBUF_OFF) {             // wbx[n][32], zero pad k>=10
        int r = idx - WBX_OFF;
        int n = r >> 5, k = r & 31;
        ws[idx] = (k < 10) ? (f16)Wbox[k * 256 + n] : (f16)0.f;
    }
}

// ---------------- k1: leaf + K=320 GEMM (one-hot fused) + max-pool -----------
// block = 8 parents = 80 child rows; grid 4096; 256 thr (4 waves x 64 feats)
__global__ __launch_bounds__(256, 3)
void k1(const float* __restrict__ box, const float* __restrict__ bbox,
        const float* __restrict__ b1, const int* __restrict__ sem,
        const int* __restrict__ nch, const f16* __restrict__ wsh,
        f16* __restrict__ xbuf) {
    __shared__ __align__(16) f16 lA[80 * LDA1];   // 52480 B

    int tid = threadIdx.x, blk = blockIdx.x;
    int w = tid >> 6, lane = tid & 63, q = lane >> 4, r16 = lane & 15;
    const f16* w1t = wsh + W1T_OFF;
    const f16* wbx = wsh + WBX_OFF;

    int nc  = nch[blk * 8 + (tid >> 5)];         // for maxpool (early)
    int sid = (tid < 80) ? sem[blk * 80 + tid] : 0;

    f32x4 acc[4][5];                             // [mt(feat)][nt(child)]

    // ---- leaf: D[feat][child] = Wbox^T(A) x box^T(B), K=32 zero-padded
    {
        f16x8 ab[4], bb[5];
        #pragma unroll
        for (int mt = 0; mt < 4; mt++)
            ab[mt] = *(const f16x8*)&wbx[(w * 64 + mt * 16 + r16) * 32 + q * 8];
        #pragma unroll
        for (int nt = 0; nt < 5; nt++) {
            const float* bp = box + (size_t)blk * 800 + (nt * 16 + r16) * 10;
            float v[8] = {0.f, 0.f, 0.f, 0.f, 0.f, 0.f, 0.f, 0.f};
            if (q == 0) {
                float2 t0 = *(const float2*)(bp + 0), t1 = *(const float2*)(bp + 2);
                float2 t2 = *(const float2*)(bp + 4), t3 = *(const float2*)(bp + 6);
                v[0] = t0.x; v[1] = t0.y; v[2] = t1.x; v[3] = t1.y;
                v[4] = t2.x; v[5] = t2.y; v[6] = t3.x; v[7] = t3.y;
            } else if (q == 1) {
                float2 t = *(const float2*)(bp + 8);
                v[0] = t.x; v[1] = t.y;
            }
            f16x8 t;
            #pragma unroll
            for (int j = 0; j < 8; j++) t[j] = (f16)v[j];
            bb[nt] = t;
        }
        #pragma unroll
        for (int mt = 0; mt < 4; mt++)
            #pragma unroll
            for (int nt = 0; nt < 5; nt++)
                acc[mt][nt] = mfma16(ab[mt], bb[nt], (f32x4){0.f, 0.f, 0.f, 0.f});
    }
    // leaf epilogue: relu(+bbox), packed b64 -> lA[child][feat]
    #pragma unroll
    for (int mt = 0; mt < 4; mt++) {
        int fb = w * 64 + mt * 16 + q * 4;
        float4 b4 = *(const float4*)&bbox[fb];
        #pragma unroll
        for (int nt = 0; nt < 5; nt++) {
            int child = nt * 16 + r16;
            f16x4 p = pack4(fmaxf(acc[mt][nt][0] + b4.x, 0.f),
                            fmaxf(acc[mt][nt][1] + b4.y, 0.f),
                            fmaxf(acc[mt][nt][2] + b4.z, 0.f),
                            fmaxf(acc[mt][nt][3] + b4.w, 0.f));
            *(f16x4*)&lA[child * LDA1 + fb] = p;
        }
    }
    // one-hot region k=256..319 (each row owned by one thread)
    if (tid < 80) {
        f16x8 z = {(f16)0.f, (f16)0.f, (f16)0.f, (f16)0.f, (f16)0.f, (f16)0.f, (f16)0.f, (f16)0.f};
        #pragma unroll
        for (int j = 0; j < 8; j++) *(f16x8*)&lA[tid * LDA1 + 256 + j * 8] = z;
        lA[tid * LDA1 + 256 + sid] = (f16)1.f;
    }

    // ---- main GEMM: K=320, weights streamed 3-deep (POST-leaf: no spills)
    #pragma unroll
    for (int mt = 0; mt < 4; mt++)
        #pragma unroll
        for (int nt = 0; nt < 5; nt++) acc[mt][nt] = (f32x4){0.f, 0.f, 0.f, 0.f};

    f16x8 aw[3][4];
    auto loadA = [&](int c, int s) {
        #pragma unroll
        for (int mt = 0; mt < 4; mt++)
            aw[s][mt] = *(const f16x8*)&w1t[(w * 64 + mt * 16 + r16) * 320 + c * 32 + q * 8];
    };
    loadA(0, 0); loadA(1, 1); loadA(2, 2);
    __syncthreads();                             // lA (leaf + one-hot) visible
    #pragma unroll
    for (int c = 0; c < 10; c++) {
        f16x8 bl[5];
        int kk = c * 32 + q * 8;
        #pragma unroll
        for (int nt = 0; nt < 5; nt++)
            bl[nt] = *(const f16x8*)&lA[(nt * 16 + r16) * LDA1 + kk];
        int s = c % 3;
        #pragma unroll
        for (int mt = 0; mt < 4; mt++)
            #pragma unroll
            for (int nt = 0; nt < 5; nt++) acc[mt][nt] = mfma16(aw[s][mt], bl[nt], acc[mt][nt]);
        if (c + 3 < 10) loadA(c + 3, s);
    }
    __syncthreads();                             // all lA reads done

    // epilogue: relu(+b1), packed b64 -> lA[child][feat] (cols 0..255)
    #pragma unroll
    for (int mt = 0; mt < 4; mt++) {
        int fb = w * 64 + mt * 16 + q * 4;
        float4 b4 = *(const float4*)&b1[fb];
        #pragma unroll
        for (int nt = 0; nt < 5; nt++) {
            int child = nt * 16 + r16;
            f16x4 p = pack4(fmaxf(acc[mt][nt][0] + b4.x, 0.f),
                            fmaxf(acc[mt][nt][1] + b4.y, 0.f),
                            fmaxf(acc[mt][nt][2] + b4.z, 0.f),
                            fmaxf(acc[mt][nt][3] + b4.w, 0.f));
            *(f16x4*)&lA[child * LDA1 + fb] = p;
        }
    }
    __syncthreads();

    // masked max over children -> xbuf dense rows (512 B aligned, monotonic)
    {
        int p = tid >> 5, g = tid & 31;
        u16x8 m = {0, 0, 0, 0, 0, 0, 0, 0};
        #pragma unroll
        for (int j = 0; j < 10; j++) {
            u16x8 v = *(const u16x8*)&lA[(p * 10 + j) * LDA1 + g * 8];
            u16x8 zz = {0, 0, 0, 0, 0, 0, 0, 0};
            v = (j < nc) ? v : zz;               // relu => nonneg => u16 max ok
            m = __builtin_elementwise_max(m, v);
        }
        int gp = blk * 8 + p;
        *(u16x8*)&xbuf[(size_t)gp * 256 + g * 8] = m;
    }
}

// ---------------- k2: sampler chain, continuous weight pipeline --------------
// block = 32 parents; grid 1024; 256 thr (4 waves x 64 feats)
__global__ __launch_bounds__(256, 3)
void k2(const f16* __restrict__ xbuf, const f16* __restrict__ wsh,
        const float* __restrict__ b2, const float* __restrict__ bs1,
        const float* __restrict__ bmu, const float* __restrict__ bvar,
        const float* __restrict__ eps, float* __restrict__ out) {
    __shared__ __align__(16) f16 actA[32 * LDX];   // 16896 B, padded rows
    __shared__ __align__(16) f16 actB[32 * LDX];

    int tid = threadIdx.x, blk = blockIdx.x;
    int w = tid >> 6, lane = tid & 63, q = lane >> 4, r16 = lane & 15;
    const f16* w2t   = wsh + W2T_OFF;
    const f16* ws1t  = w2t + 65536;
    const f16* wmut  = w2t + 2 * 65536;
    const f16* wvart = w2t + 3 * 65536;

    {   // stage x tile via regs: dense global rows -> padded LDS rows
        const f16* src = xbuf + (size_t)blk * 32 * 256;
        #pragma unroll
        for (int j = 0; j < 4; j++) {
            int slot = tid * 4 + j;              // 1024 x 16B slots, coalesced
            f16x8 v = *(const f16x8*)&src[slot * 8];
            int h = slot * 8, row = h >> 8, col = h & 255;
            *(f16x8*)&actA[row * LDX + col] = v;
        }
    }

    f32x4 acc[4][2];
    f16x8 aw[3][4];
    auto loadA = [&](const f16* wt, int c, int s) {
        #pragma unroll
        for (int mt = 0; mt < 4; mt++)
            aw[s][mt] = *(const f16x8*)&wt[(w * 64 + mt * 16 + r16) * 256 + c * 32 + q * 8];
    };
    // gemm: consumes cur (chunk c in slot c%3); tail iters (c=5,6,7 ->
    // s=2,0,1) prefetch nxt's chunk s into slot s (chunk == slot).
    auto gemm = [&](const f16* A, const f16* cur, const f16* nxt) {
        #pragma unroll
        for (int mt = 0; mt < 4; mt++)
            #pragma unroll
            for (int nt = 0; nt < 2; nt++) acc[mt][nt] = (f32x4){0.f, 0.f, 0.f, 0.f};
        #pragma unroll
        for (int c = 0; c < 8; c++) {
            f16x8 bl[2];
            int kk = c * 32 + q * 8;
            #pragma unroll
            for (int nt = 0; nt < 2; nt++)
                bl[nt] = *(const f16x8*)&A[(nt * 16 + r16) * LDX + kk];
            int s = c % 3;
            #pragma unroll
            for (int mt = 0; mt < 4; mt++)
                #pragma unroll
                for (int nt = 0; nt < 2; nt++) acc[mt][nt] = mfma16(aw[s][mt], bl[nt], acc[mt][nt]);
            if (c + 3 < 8) loadA(cur, c + 3, s);
            else if (nxt)  loadA(nxt, s, s);
        }
    };
    auto store_act = [&](f16* dst, const float* bias) {
        #pragma unroll
        for (int mt = 0; mt < 4; mt++) {
            int fb = w * 64 + mt * 16 + q * 4;
            float4 b4 = *(const float4*)&bias[fb];
            #pragma unroll
            for (int nt = 0; nt < 2; nt++) {
                int par = nt * 16 + r16;
                f16x4 p = pack4(fmaxf(acc[mt][nt][0] + b4.x, 0.f),
                                fmaxf(acc[mt][nt][1] + b4.y, 0.f),
                                fmaxf(acc[mt][nt][2] + b4.z, 0.f),
                                fmaxf(acc[mt][nt][3] + b4.w, 0.f));
                *(f16x4*)&dst[par * LDX + fb] = p;
            }
        }
    };

    // stage1: parent_feat = relu(x @ W2 + b2) -> actB
    loadA(w2t, 0, 0); loadA(w2t, 1, 1); loadA(w2t, 2, 2);
    __syncthreads();                             // actA staging visible
    gemm(actA, w2t, ws1t);
    store_act(actB, b2);
    __syncthreads();

    // stage2: enc = relu(parent @ Ws1 + bs1) -> actA
    gemm(actB, ws1t, wmut);
    store_act(actA, bs1);
    __syncthreads();

    // stage3: mu -> regs (prefetches wvart in tail)
    gemm(actA, wmut, wvart);
    f32x4 mu[4][2];
    #pragma unroll
    for (int mt = 0; mt < 4; mt++)
        #pragma unroll
        for (int nt = 0; nt < 2; nt++) mu[mt][nt] = acc[mt][nt];

    // stage4: logvar (actA unchanged: no barrier, pipeline stays hot)
    gemm(actA, wvart, nullptr);

    // fused sampler epilogue, float4 io
    #pragma unroll
    for (int mt = 0; mt < 4; mt++) {
        int fb = w * 64 + mt * 16 + q * 4;
        float4 bm4 = *(const float4*)&bmu[fb];
        float4 bv4 = *(const float4*)&bvar[fb];
        #pragma unroll
        for (int nt = 0; nt < 2; nt++) {
            size_t gp = (size_t)blk * 32 + nt * 16 + r16;
            float4 ev = *(const float4*)&eps[gp * 256 + fb];
            float m0 = mu[mt][nt][0] + bm4.x, l0 = acc[mt][nt][0] + bv4.x;
            float m1 = mu[mt][nt][1] + bm4.y, l1 = acc[mt][nt][1] + bv4.y;
            float m2 = mu[mt][nt][2] + bm4.z, l2 = acc[mt][nt][2] + bv4.z;
            float m3 = mu[mt][nt][3] + bm4.w, l3 = acc[mt][nt][3] + bv4.w;
            float e0 = expf(l0), e1 = expf(l1), e2 = expf(l2), e3 = expf(l3);
            float4 s4 = {ev.x * sqrtf(e0) + m0, ev.y * sqrtf(e1) + m1,
                         ev.z * sqrtf(e2) + m2, ev.w * sqrtf(e3) + m3};
            float4 k4 = {1.f + l0 - m0 * m0 - e0, 1.f + l1 - m1 * m1 - e1,
                         1.f + l2 - m2 * m2 - e2, 1.f + l3 - m3 * m3 - e3};
            *(float4*)&out[gp * 512 + fb]       = s4;
            *(float4*)&out[gp * 512 + 256 + fb] = k4;
        }
    }
}

// ---------------------------------------------------------------------------
extern "C" void kernel_launch(void* const* d_in, const int* in_sizes, int n_in,
                              void* d_out, int out_size, void* d_ws, size_t ws_size,
                              hipStream_t stream) {
    const float* box  = (const float*)d_in[0];
    const float* eps  = (const float*)d_in[1];
    const float* Wbox = (const float*)d_in[2];
    const float* bbox = (const float*)d_in[3];
    const float* W1   = (const float*)d_in[4];
    const float* b1   = (const float*)d_in[5];
    const float* W2   = (const float*)d_in[6];
    const float* b2   = (const float*)d_in[7];
    const float* Ws1  = (const float*)d_in[8];
    const float* bs1  = (const float*)d_in[9];
    const float* Wmu  = (const float*)d_in[10];
    const float* bmu  = (const float*)d_in[11];
    const float* Wvar = (const float*)d_in[12];
    const float* bvar = (const float*)d_in[13];
    const int*   sem  = (const int*)d_in[14];
    const int*   nch  = (const int*)d_in[15];

    f16* wsh  = (f16*)d_ws;
    f16* xbuf = wsh + XBUF_OFF;

    kconv<<<XBUF_OFF / 256, 256, 0, stream>>>(W1, W2, Ws1, Wmu, Wvar, Wbox, wsh);
    k1<<<NPAR / 8, 256, 0, stream>>>(box, bbox, b1, sem, nch, wsh, xbuf);
    k2<<<NPAR / 32, 256, 0, stream>>>(xbuf, wsh, b2, bs1, bmu, bvar, eps, (float*)d_out);
}